// Round 12
// baseline (197.979 us; speedup 1.0000x reference)
//
#include <hip/hip_runtime.h>
#include <hip/hip_cooperative_groups.h>

namespace cg = cooperative_groups;

// SoftTimeAttention: out[b,q,:] = sum_j softmax_j(-(T*(t_q-t_j))^2) * h[b,j,:]
// B=4, T=4096, H=256, f32. ts = 4096*t; w = exp(-(ts_q-ts_j)^2) == 0 exactly in
// f32 for |dts| > 12; margin-2 bucket window (bucket width 4) keeps all terms
// >= e^-64 (identical coverage to the proven R4/R11 kernel).
//
// R12: single cooperative dispatch replacing {serial 4-block sort -> gap ->
// main}: parallel build (16384 threads, atomicAdd rank into padded per-bucket
// lists) -> grid.sync -> scan (blocks 0-3: bucket-offset prefix + pos->bucket
// inverse map) -> grid.sync -> main (R4's exact quad-row ballot loop over the
// padded window slots; sentinel slots self-exclude via w==0).

constexpr int Bb   = 4;
constexpr int Tt   = 4096;
constexpr int Hh   = 256;
constexpr int NBK  = 1024;
constexpr int CAP  = 32;      // per-bucket capacity; P(Poisson(4)>32) ~ 1e-19
constexpr int ECAP = 512;     // extras capacity (overflow elements)

// ws layout (bytes)
constexpr size_t CNT_BYTES = (size_t)Bb * NBK * 4;                    // 16384
constexpr size_t NEX_OFF   = CNT_BYTES;                               // int
constexpr size_t OFF_OFF   = NEX_OFF + 64;
constexpr size_t OFF_BYTES = (size_t)Bb * (NBK + 1) * 4;              // 16400
constexpr size_t P2K_OFF   = ((OFF_OFF + OFF_BYTES + 63) / 64) * 64;
constexpr size_t P2K_BYTES = (size_t)Bb * Tt * 2;                     // 32768
constexpr size_t EXT_OFF   = ((P2K_OFF + P2K_BYTES + 63) / 64) * 64;
constexpr size_t EXT_BYTES = (size_t)ECAP * 8;
constexpr size_t LST_OFF   = ((EXT_OFF + EXT_BYTES + 63) / 64) * 64;
constexpr size_t LST_BYTES = (size_t)Bb * NBK * CAP * 8;              // 1 MB
constexpr size_t WS_NEED   = LST_OFF + LST_BYTES;

__device__ __forceinline__ int bucket_of(float ts) {
    int kk = (int)(ts * 0.25f);
    return kk < 0 ? 0 : (kk > NBK - 1 ? NBK - 1 : kk);
}

__global__ __launch_bounds__(256, 2) void stattn_coop(
    const float* __restrict__ h_seq,
    const float* __restrict__ tvals,
    float* __restrict__ out,
    char* __restrict__ ws)
{
    int*            cnt    = (int*)(ws);
    int*            nex    = (int*)(ws + NEX_OFF);
    int*            offA   = (int*)(ws + OFF_OFF);
    unsigned short* p2k    = (unsigned short*)(ws + P2K_OFF);
    uint2*          extras = (uint2*)(ws + EXT_OFF);
    uint2*          lists  = (uint2*)(ws + LST_OFF);

    cg::grid_group grid = cg::this_grid();

    const int tid  = threadIdx.x;
    const int lane = tid & 63;
    const int wv   = tid >> 6;

    // ---- phase 1: build padded bucket lists (one element per thread)
    {
        const int gid = blockIdx.x * 256 + tid;
        if (gid < Bb * Tt) {
            const int b = gid >> 12;
            const int j = gid & (Tt - 1);
            const float ts = tvals[(size_t)b * Tt + j] * 4096.0f;
            const int k = bucket_of(ts);
            const int rank = atomicAdd(&cnt[b * NBK + k], 1);
            if (rank < CAP) {
                uint2 pr; pr.x = __float_as_uint(ts); pr.y = (unsigned)j;
                lists[((size_t)(b * NBK + k)) * CAP + rank] = pr;
            } else {
                const int e = atomicAdd(nex, 1);
                if (e < ECAP) {
                    uint2 pr; pr.x = __float_as_uint(ts);
                    pr.y = (unsigned)(j | (b << 12));
                    extras[e] = pr;
                }
            }
        }
    }
    __threadfence();
    grid.sync();

    // ---- phase 2: per-batch offset prefix + pos->bucket map (blocks 0..3)
    {
        __shared__ int wtot[4], wexc[4];
        if (blockIdx.x < (unsigned)Bb) {
            const int b = blockIdx.x;
            int c[4]; int s = 0;
            #pragma unroll
            for (int u = 0; u < 4; ++u) {
                int cc = cnt[b * NBK + tid * 4 + u];
                cc = cc > CAP ? CAP : cc;
                c[u] = cc; s += cc;
            }
            int x = s;
            #pragma unroll
            for (int d = 1; d < 64; d <<= 1) {
                const int y = __shfl_up(x, d);
                if (lane >= d) x += y;
            }
            if (lane == 63) wtot[wv] = x;
            __syncthreads();
            if (tid < 4) {
                int y = wtot[tid];
                #pragma unroll
                for (int d = 1; d < 4; d <<= 1) {
                    const int z = __shfl_up(y, d);
                    if (tid >= d) y += z;
                }
                wexc[tid] = y - wtot[tid];
            }
            __syncthreads();
            int o = (x - s) + wexc[wv];
            #pragma unroll
            for (int u = 0; u < 4; ++u) {
                offA[(size_t)b * (NBK + 1) + tid * 4 + u] = o;
                for (int r = 0; r < c[u]; ++r)
                    p2k[(size_t)b * Tt + o + r] = (unsigned short)(tid * 4 + u);
                o += c[u];
            }
            if (tid == 255) offA[(size_t)b * (NBK + 1) + NBK] = o;
        }
    }
    __threadfence();
    grid.sync();

    // ---- phase 3: main (R4-identical math on padded window slots)
    const int phys = blockIdx.x;
    const int lb   = (phys & 7) * 64 + (phys >> 3);   // XCD-contiguous swizzle
    const int b    = lb >> 7;
    const int blk  = lb & 127;

    const float* hb   = h_seq + (size_t)b * Tt * Hh;
    const int*   offb = offA + (size_t)b * (NBK + 1);
    const int ne = *nex;

    if (ne > ECAP) {
        // pathological input: exact dense fallback over original indices
        const float* tb = tvals + (size_t)b * Tt;
        for (int g = wv; g < 32; g += 4) {
            const int q = blk * 32 + g;
            const float tsq = tb[q] * 4096.0f;
            float4 acc = make_float4(0.f,0.f,0.f,0.f);
            float den = 0.f;
            for (int key = 0; key < Tt; ++key) {
                const float x = tsq - tb[key] * 4096.0f;
                const float w = __expf(-x * x);
                den += w;
                if (w > 0.f) {
                    const float4 hv = *(const float4*)&hb[(size_t)key * Hh + lane * 4];
                    acc.x += w * hv.x; acc.y += w * hv.y;
                    acc.z += w * hv.z; acc.w += w * hv.w;
                }
            }
            const float inv = 1.0f / den;
            float4 o;
            o.x = acc.x*inv; o.y = acc.y*inv; o.z = acc.z*inv; o.w = acc.w*inv;
            *(float4*)&out[((size_t)b * Tt + q) * Hh + lane * 4] = o;
        }
        return;
    }

    const int p0  = blk * 32 + wv * 8;
    const int n_s = offb[NBK];
    int nval = n_s - p0; nval = nval < 0 ? 0 : (nval > 8 ? 8 : nval);

    if (nval > 0) {
        // O(1) query fetch via inverse map (lane g<8 fetches query p0+g)
        int myk = 0; float myts = -3.0e18f; int myidx = 0;
        if (lane < 8) {
            const int p = p0 + lane;
            if (p < n_s) {
                myk = (int)p2k[(size_t)b * Tt + p];
                const int r = p - offb[myk];
                const uint2 e = lists[((size_t)(b * NBK + myk)) * CAP + r];
                myts = __uint_as_float(e.x);
                myidx = (int)e.y;
            }
        }
        float tq[8]; int qi[8];
        #pragma unroll
        for (int g = 0; g < 8; ++g) { tq[g] = __shfl(myts, g); qi[g] = __shfl(myidx, g); }
        const int bmin = __shfl(myk, 0);
        const int bmax = __shfl(myk, nval - 1);

        const int blo = bmin - 2 < 0 ? 0 : bmin - 2;
        const int bhi = bmax + 3 > NBK ? NBK : bmax + 3;
        const int nslots = (bhi - blo) << 5;     // CAP = 32

        float4 acc[8];
        float  den[8];
        #pragma unroll
        for (int g = 0; g < 8; ++g) { acc[g] = make_float4(0.f,0.f,0.f,0.f); den[g] = 0.f; }

        for (int base = 0; base < nslots; base += 64) {
            const int slot = base + lane;
            const bool inr = slot < nslots;
            const int wb = blo + (slot >> 5);
            const int wbc = wb < NBK - 1 ? wb : NBK - 1;
            int cv = cnt[b * NBK + wbc];
            cv = cv > CAP ? CAP : cv;
            const bool valid = inr && ((slot & 31) < cv);

            float tj; int jj;
            if (valid) {
                const uint2 e = lists[((size_t)(b * NBK + wb)) * CAP + (slot & 31)];
                tj = __uint_as_float(e.x); jj = (int)e.y;
            } else { tj = 3.0e18f; jj = 0; }     // sentinel -> w == 0 exactly

            float w[8]; float wmax = 0.f;
            #pragma unroll
            for (int g = 0; g < 8; ++g) {
                const float x = tq[g] - tj;
                w[g] = __expf(-x * x);
                den[g] += w[g];
                wmax = fmaxf(wmax, w[g]);
            }

            unsigned long long mask = __ballot(wmax > 1e-20f);
            while (mask) {
                const int s0 = __builtin_ctzll(mask); mask &= mask - 1;
                const bool h1 = mask != 0;
                const int s1 = h1 ? __builtin_ctzll(mask) : s0; if (h1) mask &= mask - 1;
                const bool h2 = mask != 0;
                const int s2 = h2 ? __builtin_ctzll(mask) : s0; if (h2) mask &= mask - 1;
                const bool h3 = mask != 0;
                const int s3 = h3 ? __builtin_ctzll(mask) : s0; if (h3) mask &= mask - 1;

                const int j0 = __shfl(jj, s0);
                const int j1 = __shfl(jj, s1);
                const int j2 = __shfl(jj, s2);
                const int j3 = __shfl(jj, s3);
                float4 h0  = *(const float4*)&hb[(size_t)j0 * Hh + lane * 4];
                float4 h1v = *(const float4*)&hb[(size_t)j1 * Hh + lane * 4];
                float4 h2v = *(const float4*)&hb[(size_t)j2 * Hh + lane * 4];
                float4 h3v = *(const float4*)&hb[(size_t)j3 * Hh + lane * 4];
                if (!h1) h1v = make_float4(0.f,0.f,0.f,0.f);
                if (!h2) h2v = make_float4(0.f,0.f,0.f,0.f);
                if (!h3) h3v = make_float4(0.f,0.f,0.f,0.f);

                #pragma unroll
                for (int g = 0; g < 8; ++g) {
                    const float a0 = __shfl(w[g], s0);
                    const float a1 = __shfl(w[g], s1);
                    const float a2 = __shfl(w[g], s2);
                    const float a3 = __shfl(w[g], s3);
                    acc[g].x += a0 * h0.x + a1 * h1v.x + a2 * h2v.x + a3 * h3v.x;
                    acc[g].y += a0 * h0.y + a1 * h1v.y + a2 * h2v.y + a3 * h3v.y;
                    acc[g].z += a0 * h0.z + a1 * h1v.z + a2 * h2v.z + a3 * h3v.z;
                    acc[g].w += a0 * h0.w + a1 * h1v.w + a2 * h2v.w + a3 * h3v.w;
                }
            }
        }

        // extras as keys (overflow elements excluded from lists): exact add
        for (int e = 0; e < ne; ++e) {
            const uint2 ex = extras[e];
            if ((int)((ex.y >> 12) & 3) != b) continue;
            const float tj = __uint_as_float(ex.x);
            const int jj = (int)(ex.y & (Tt - 1));
            const float4 hv = *(const float4*)&hb[(size_t)jj * Hh + lane * 4];
            #pragma unroll
            for (int g = 0; g < 8; ++g) {
                const float x = tq[g] - tj;
                const float w = __expf(-x * x);
                if (lane == 0) den[g] += w;      // den is lane-summed below
                acc[g].x += w * hv.x; acc[g].y += w * hv.y;
                acc[g].z += w * hv.z; acc[g].w += w * hv.w;
            }
        }

        #pragma unroll
        for (int g = 0; g < 8; ++g) {
            float d = den[g];
            #pragma unroll
            for (int s = 1; s < 64; s <<= 1) d += __shfl_xor(d, s);
            den[g] = d;
        }

        #pragma unroll
        for (int g = 0; g < 8; ++g) {
            if (g < nval) {
                const float inv = 1.0f / den[g];
                float* orow = out + ((size_t)b * Tt + qi[g]) * Hh + lane * 4;
                float4 o;
                o.x = acc[g].x * inv; o.y = acc[g].y * inv;
                o.z = acc[g].z * inv; o.w = acc[g].w * inv;
                *(float4*)orow = o;
            }
        }
    }

    // extras as queries (elements not in lists): dense, block phys==0 only
    if (phys == 0 && ne > 0) {
        const int nee = ne < ECAP ? ne : ECAP;
        for (int e = wv; e < nee; e += 4) {
            const uint2 ex = extras[e];
            const int eb = (int)((ex.y >> 12) & 3);
            const int q  = (int)(ex.y & (Tt - 1));
            const float tsq = __uint_as_float(ex.x);
            const float* tbe = tvals + (size_t)eb * Tt;
            const float* hbe = h_seq + (size_t)eb * Tt * Hh;
            float4 acc = make_float4(0.f,0.f,0.f,0.f);
            float den = 0.f;
            for (int key = 0; key < Tt; ++key) {
                const float x = tsq - tbe[key] * 4096.0f;
                const float w = __expf(-x * x);
                den += w;
                if (w > 0.f) {
                    const float4 hv = *(const float4*)&hbe[(size_t)key * Hh + lane * 4];
                    acc.x += w * hv.x; acc.y += w * hv.y;
                    acc.z += w * hv.z; acc.w += w * hv.w;
                }
            }
            const float inv = 1.0f / den;
            float4 o;
            o.x = acc.x*inv; o.y = acc.y*inv; o.z = acc.z*inv; o.w = acc.w*inv;
            *(float4*)&out[((size_t)eb * Tt + q) * Hh + lane * 4] = o;
        }
    }
}

// ---------------------------------------------------------------------------
// Naive dense fallback if ws is too small (never expected).
__global__ __launch_bounds__(64) void stattn_naive(
    const float* __restrict__ h_seq,
    const float* __restrict__ tvals,
    float* __restrict__ out)
{
    const int gid  = blockIdx.x;
    const int b    = gid >> 12;
    const int q    = gid & (Tt - 1);
    const int lane = threadIdx.x;
    const float* tb = tvals + (size_t)b * Tt;
    const float* hb = h_seq + (size_t)b * Tt * Hh;
    const float tsq = tb[q] * 4096.0f;
    float4 acc = make_float4(0.f,0.f,0.f,0.f);
    float den = 0.f;
    for (int j = 0; j < Tt; ++j) {
        const float x = tsq - tb[j] * 4096.0f;
        const float w = __expf(-x * x);
        den += w;
        if (w > 0.f) {
            const float4 hv = *(const float4*)&hb[(size_t)j * Hh + lane * 4];
            acc.x += w * hv.x; acc.y += w * hv.y;
            acc.z += w * hv.z; acc.w += w * hv.w;
        }
    }
    const float inv = 1.0f / den;
    float4 o;
    o.x = acc.x * inv; o.y = acc.y * inv; o.z = acc.z * inv; o.w = acc.w * inv;
    *(float4*)&out[((size_t)b * Tt + q) * Hh + lane * 4] = o;
}

extern "C" void kernel_launch(void* const* d_in, const int* in_sizes, int n_in,
                              void* d_out, int out_size, void* d_ws, size_t ws_size,
                              hipStream_t stream) {
    const float* h_seq = (const float*)d_in[0];
    const float* tvals = (const float*)d_in[1];
    float* out = (float*)d_out;
    char* wsc = (char*)d_ws;

    if (ws_size >= WS_NEED) {
        hipMemsetAsync(d_ws, 0, CNT_BYTES + 64, stream);   // cnt + nextra
        void* kargs[] = { (void*)&h_seq, (void*)&tvals, (void*)&out, (void*)&wsc };
        hipLaunchCooperativeKernel((const void*)stattn_coop,
                                   dim3(512), dim3(256), kargs, 0, stream);
    } else {
        stattn_naive<<<dim3(Bb * Tt), dim3(64), 0, stream>>>(h_seq, tvals, out);
    }
}

// Round 13
// 22.621 us; speedup vs baseline: 8.7521x; 8.7521x over previous
//
#include <hip/hip_runtime.h>
#include <hip/hip_bf16.h>

// SoftTimeAttention: out[b,q,:] = sum_j softmax_j(-(T*(t_q-t_j))^2) * h[b,j,:]
// B=4, T=4096, H=256, f32. w = exp(-(4096*dt)^2) == 0 in f32 for |dt| > ~2.3e-3
// => ~19 active keys per query. Bucket-sort t (1024 buckets), process queries in
// sorted order; each wave shares one candidate window across QPW queries.
//
// R13 = restoration of the session champion (R4/R11, 22.4-22.9 us, replicated
// twice). All structural alternatives tested in R5-R12 regressed:
// fused single-kernel (29-32), parallel-build multi-dispatch (32),
// geometry variants (28.5-29.3), cooperative grid-sync (198).

constexpr int Bb = 4;
constexpr int Tt = 4096;
constexpr int Hh = 256;
constexpr int NB = 1024;     // t-buckets per batch
// coverage: |dt| <= 2/1024 <=> w >= exp(-64); buckets [k-2, k+2] suffice.

// ---------------------------------------------------------------------------
// Per-batch counting sort. One block (1024 thr) per batch.
// Output: spair[b][pos] = { bitcast(t*4096), original_idx }, offsets[b][NB+1].
__global__ __launch_bounds__(1024) void sort_kernel(
    const float* __restrict__ tvals,
    uint2* __restrict__ spair,
    int* __restrict__ offsets)
{
    __shared__ int hist[NB];
    __shared__ int excl[NB];
    __shared__ int cnt[NB];
    __shared__ int wsum[16];
    __shared__ int wexcl[16];

    const int b    = blockIdx.x;
    const int tid  = threadIdx.x;
    const int lane = tid & 63;
    const int wv   = tid >> 6;
    const float* tb = tvals + (size_t)b * Tt;

    hist[tid] = 0;
    cnt[tid]  = 0;
    __syncthreads();

    float tv[4]; int bk[4];
    #pragma unroll
    for (int i = 0; i < 4; ++i) {
        const int j = i * 1024 + tid;
        const float t = tb[j];
        int k = (int)(t * (float)NB);
        k = k < 0 ? 0 : (k > NB - 1 ? NB - 1 : k);
        tv[i] = t * 4096.0f;      // pre-scaled for the main kernel
        bk[i] = k;
        atomicAdd(&hist[k], 1);
    }
    __syncthreads();

    // inclusive scan over 1024 buckets: wave scan + cross-wave fixup
    const int self = hist[tid];
    int x = self;
    #pragma unroll
    for (int d = 1; d < 64; d <<= 1) {
        const int y = __shfl_up(x, d);
        if (lane >= d) x += y;
    }
    if (lane == 63) wsum[wv] = x;
    __syncthreads();
    if (tid < 16) {
        int y = wsum[tid];
        #pragma unroll
        for (int d = 1; d < 16; d <<= 1) {
            const int z = __shfl_up(y, d);
            if (tid >= d) y += z;
        }
        wexcl[tid] = y - wsum[tid];
    }
    __syncthreads();
    const int incl = x + wexcl[wv];
    excl[tid] = incl - self;
    offsets[(size_t)b * (NB + 1) + tid] = incl - self;
    if (tid == 0) offsets[(size_t)b * (NB + 1) + NB] = Tt;
    __syncthreads();

    #pragma unroll
    for (int i = 0; i < 4; ++i) {
        const int k = bk[i];
        const int rank = atomicAdd(&cnt[k], 1);
        const int pos = excl[k] + rank;
        uint2 pr;
        pr.x = __float_as_uint(tv[i]);
        pr.y = (unsigned)(i * 1024 + tid);
        spair[(size_t)b * Tt + pos] = pr;
    }
}

// ---------------------------------------------------------------------------
// Main sparse kernel: 256 thr = 4 waves; each wave handles QPW=8 consecutive
// sorted queries (shared candidate window). Grid = B * T/32 = 512 blocks.
constexpr int QPW = 8;
constexpr int MTHREADS = 256;

__global__ __launch_bounds__(MTHREADS) void stattn_sparse(
    const float* __restrict__ h_seq,
    const uint2* __restrict__ spair,
    const int* __restrict__ offsets,
    float* __restrict__ out)
{
    const int tid  = threadIdx.x;
    const int lane = tid & 63;
    const int wv   = tid >> 6;

    // XCD-contiguous swizzle (512 blocks = 8 XCDs x 64): 2 XCDs per batch.
    const int phys = blockIdx.x;
    const int lb   = (phys & 7) * 64 + (phys >> 3);
    const int b    = lb >> 7;
    const int blk  = lb & 127;

    const uint2* sp  = spair + (size_t)b * Tt;
    const int*   off = offsets + (size_t)b * (NB + 1);
    const float* hb  = h_seq + (size_t)b * Tt * Hh;

    const int p0 = blk * 32 + wv * QPW;

    float tq[QPW]; int qi[QPW];
    #pragma unroll
    for (int g = 0; g < QPW; ++g) {
        const uint2 pr = sp[p0 + g];
        tq[g] = __uint_as_float(pr.x);     // t*4096
        qi[g] = (int)pr.y;
    }

    // candidate window (buckets nondecreasing along sorted positions)
    // bucket = floor(t*1024) = floor(ts * 0.25)
    int bmin = (int)(tq[0] * 0.25f);
    int bmax = (int)(tq[QPW - 1] * 0.25f);
    bmin = bmin < 0 ? 0 : (bmin > NB - 1 ? NB - 1 : bmin);
    bmax = bmax < 0 ? 0 : (bmax > NB - 1 ? NB - 1 : bmax);
    const int blo = bmin - 2 < 0 ? 0 : bmin - 2;
    const int bhi = bmax + 3 > NB ? NB : bmax + 3;
    const int lo = off[blo];
    const int hi = off[bhi];

    float4 acc[QPW];
    float  den[QPW];
    #pragma unroll
    for (int g = 0; g < QPW; ++g) {
        acc[g] = make_float4(0.f, 0.f, 0.f, 0.f);
        den[g] = 0.f;
    }

    for (int base = lo; base < hi; base += 64) {
        const int p = base + lane;
        const bool valid = p < hi;
        float tj; int jj;
        if (valid) { const uint2 pr = sp[p]; tj = __uint_as_float(pr.x); jj = (int)pr.y; }
        else       { tj = 3.0e18f; jj = 0; }   // -> w == 0 exactly

        float w[QPW]; float wmax = 0.f;
        #pragma unroll
        for (int g = 0; g < QPW; ++g) {
            const float x = tq[g] - tj;
            w[g] = __expf(-x * x);
            den[g] += w[g];
            wmax = fmaxf(wmax, w[g]);
        }

        unsigned long long mask = __ballot(wmax > 1e-20f);
        while (mask) {
            const int s0 = __builtin_ctzll(mask); mask &= mask - 1;
            const bool h1 = mask != 0;
            const int s1 = h1 ? __builtin_ctzll(mask) : s0; if (h1) mask &= mask - 1;
            const bool h2 = mask != 0;
            const int s2 = h2 ? __builtin_ctzll(mask) : s0; if (h2) mask &= mask - 1;
            const bool h3 = mask != 0;
            const int s3 = h3 ? __builtin_ctzll(mask) : s0; if (h3) mask &= mask - 1;

            const int j0 = __shfl(jj, s0);
            const int j1 = __shfl(jj, s1);
            const int j2 = __shfl(jj, s2);
            const int j3 = __shfl(jj, s3);
            float4 h0 = *(const float4*)&hb[(size_t)j0 * Hh + lane * 4];
            float4 h1v = *(const float4*)&hb[(size_t)j1 * Hh + lane * 4];
            float4 h2v = *(const float4*)&hb[(size_t)j2 * Hh + lane * 4];
            float4 h3v = *(const float4*)&hb[(size_t)j3 * Hh + lane * 4];
            // mask out duplicated slots once (amortized over all QPW queries)
            if (!h1) { h1v.x = 0.f; h1v.y = 0.f; h1v.z = 0.f; h1v.w = 0.f; }
            if (!h2) { h2v.x = 0.f; h2v.y = 0.f; h2v.z = 0.f; h2v.w = 0.f; }
            if (!h3) { h3v.x = 0.f; h3v.y = 0.f; h3v.z = 0.f; h3v.w = 0.f; }

            #pragma unroll
            for (int g = 0; g < QPW; ++g) {
                const float a0 = __shfl(w[g], s0);
                const float a1 = __shfl(w[g], s1);
                const float a2 = __shfl(w[g], s2);
                const float a3 = __shfl(w[g], s3);
                acc[g].x += a0 * h0.x; acc[g].y += a0 * h0.y;
                acc[g].z += a0 * h0.z; acc[g].w += a0 * h0.w;
                acc[g].x += a1 * h1v.x; acc[g].y += a1 * h1v.y;
                acc[g].z += a1 * h1v.z; acc[g].w += a1 * h1v.w;
                acc[g].x += a2 * h2v.x; acc[g].y += a2 * h2v.y;
                acc[g].z += a2 * h2v.z; acc[g].w += a2 * h2v.w;
                acc[g].x += a3 * h3v.x; acc[g].y += a3 * h3v.y;
                acc[g].z += a3 * h3v.z; acc[g].w += a3 * h3v.w;
            }
        }
    }

    // reduce denominators across lanes
    #pragma unroll
    for (int g = 0; g < QPW; ++g) {
        float d = den[g];
        #pragma unroll
        for (int s = 1; s < 64; s <<= 1) d += __shfl_xor(d, s);
        den[g] = d;
    }

    #pragma unroll
    for (int g = 0; g < QPW; ++g) {
        const float inv = 1.0f / den[g];
        float* orow = out + ((size_t)b * Tt + qi[g]) * Hh + lane * 4;
        float4 o;
        o.x = acc[g].x * inv; o.y = acc[g].y * inv;
        o.z = acc[g].z * inv; o.w = acc[g].w * inv;
        *(float4*)orow = o;
    }
}

// ---------------------------------------------------------------------------
// Fallback dense f32 kernel (round-1 proven) if ws is too small.
constexpr int QB = 64;
constexpr int JB = 64;
constexpr int NT = Tt / JB;
constexpr int NTHREADS = 512;

__device__ __forceinline__ void gld16(const void* g, void* l) {
    __builtin_amdgcn_global_load_lds(
        (const __attribute__((address_space(1))) void*)g,
        (__attribute__((address_space(3))) void*)l, 16, 0, 0);
}
__device__ __forceinline__ void gld4(const void* g, void* l) {
    __builtin_amdgcn_global_load_lds(
        (const __attribute__((address_space(1))) void*)g,
        (__attribute__((address_space(3))) void*)l, 4, 0, 0);
}

__global__ __launch_bounds__(NTHREADS, 2) void stattn_kernel(
    const float* __restrict__ h_seq,
    const float* __restrict__ tvals,
    float* __restrict__ out)
{
    __shared__ float hbuf[2][JB][Hh];
    __shared__ float wbuf[JB][QB];
    __shared__ float tjbuf[2][JB];
    __shared__ float sden[QB];
    __shared__ float tqs[QB];

    const int tid  = threadIdx.x;
    const int lane = tid & 63;
    const int wv   = tid >> 6;
    const int phys = blockIdx.x;
    const int lb   = (phys & 7) * 32 + (phys >> 3);
    const int b    = lb >> 6;
    const int qt   = lb & 63;
    const int q0   = qt * QB;

    const float* hb = h_seq + (size_t)b * Tt * Hh;
    const float* tb = tvals + (size_t)b * Tt;

    if (tid < QB) { tqs[tid] = tb[q0 + tid]; sden[tid] = 0.0f; }

    float acc[8][4];
    #pragma unroll
    for (int k = 0; k < 8; ++k)
        #pragma unroll
        for (int c = 0; c < 4; ++c) acc[k][c] = 0.0f;

    const float Tf = (float)Tt;

    auto stage = [&](int buf, int tile) {
        const float* src = hb + (size_t)tile * JB * Hh;
        float* dst = &hbuf[buf][0][0];
        #pragma unroll
        for (int i = 0; i < 8; ++i) {
            const int off = i * (NTHREADS * 4) + tid * 4;
            gld16(src + off, dst + off);
        }
        gld4(tb + tile * JB + lane, &tjbuf[buf][lane]);
    };

    stage(0, 0);
    __syncthreads();

    const int qw = wv * 8;

    for (int t = 0; t < NT; ++t) {
        const int cur = t & 1;
        __syncthreads();
        {
            const int q  = tid & 63;
            const int jg = tid >> 6;
            const float tqv = tqs[q];
            const float4 tj0 = *(const float4*)&tjbuf[cur][jg * 8];
            const float4 tj1 = *(const float4*)&tjbuf[cur][jg * 8 + 4];
            const float tjv[8] = {tj0.x, tj0.y, tj0.z, tj0.w,
                                  tj1.x, tj1.y, tj1.z, tj1.w};
            float part = 0.0f;
            #pragma unroll
            for (int jj = 0; jj < 8; ++jj) {
                const float d = Tf * (tqv - tjv[jj]);
                const float w = __expf(-d * d);
                wbuf[jg * 8 + jj][q] = w;
                part += w;
            }
            atomicAdd(&sden[q], part);
        }
        if (t + 1 < NT) stage((t + 1) & 1, t + 1);
        asm volatile("s_waitcnt lgkmcnt(0)" ::: "memory");
        __builtin_amdgcn_s_barrier();
        asm volatile("" ::: "memory");
        #pragma unroll 2
        for (int j = 0; j < JB; ++j) {
            const float4 hv = *(const float4*)&hbuf[cur][j][lane * 4];
            const float4 w0 = *(const float4*)&wbuf[j][qw];
            const float4 w1 = *(const float4*)&wbuf[j][qw + 4];
            const float wr[8] = {w0.x, w0.y, w0.z, w0.w,
                                 w1.x, w1.y, w1.z, w1.w};
            #pragma unroll
            for (int k = 0; k < 8; ++k) {
                acc[k][0] += wr[k] * hv.x;
                acc[k][1] += wr[k] * hv.y;
                acc[k][2] += wr[k] * hv.z;
                acc[k][3] += wr[k] * hv.w;
            }
        }
    }

    #pragma unroll
    for (int k = 0; k < 8; ++k) {
        const int q = q0 + qw + k;
        const float inv = 1.0f / sden[qw + k];
        float4 o;
        o.x = acc[k][0] * inv;
        o.y = acc[k][1] * inv;
        o.z = acc[k][2] * inv;
        o.w = acc[k][3] * inv;
        *(float4*)&out[((size_t)b * Tt + q) * Hh + (size_t)(lane * 4)] = o;
    }
}

extern "C" void kernel_launch(void* const* d_in, const int* in_sizes, int n_in,
                              void* d_out, int out_size, void* d_ws, size_t ws_size,
                              hipStream_t stream) {
    const float* h_seq = (const float*)d_in[0];
    const float* tvals = (const float*)d_in[1];
    float* out = (float*)d_out;

    // ws layout: spair (B*T uint2) | offsets (B*(NB+1) i32)
    const size_t need = (size_t)Bb * Tt * sizeof(uint2) + (size_t)Bb * (NB + 1) * 4;
    if (ws_size >= need) {
        uint2* spair  = (uint2*)d_ws;
        int*   offsets = (int*)(spair + (size_t)Bb * Tt);
        sort_kernel<<<dim3(Bb), dim3(1024), 0, stream>>>(tvals, spair, offsets);
        stattn_sparse<<<dim3(Bb * (Tt / 32)), dim3(MTHREADS), 0, stream>>>(
            h_seq, spair, offsets, out);
    } else {
        stattn_kernel<<<dim3(Bb * (Tt / QB)), dim3(NTHREADS), 0, stream>>>(
            h_seq, tvals, out);
    }
}

// Round 14
// 21.326 us; speedup vs baseline: 9.2832x; 1.0607x over previous
//
#include <hip/hip_runtime.h>
#include <hip/hip_bf16.h>

// SoftTimeAttention: out[b,q,:] = sum_j softmax_j(-(T*(t_q-t_j))^2) * h[b,j,:]
// B=4, T=4096, H=256, f32. w = exp(-(4096*dt)^2) == 0 in f32 for |dt| > ~2.3e-3
// => ~19 active keys per query. Bucket-sort t (1024 buckets), process queries in
// sorted order; each wave shares one candidate window across QPW queries.
//
// R14 = champion (R4/R11/R13: 22.4-22.9 us, 3x replicated) + two micro-opts:
//  (a) sort reuses the rank returned by the pass-1 atomicAdd (removes the
//      second 16K-atomic round and the cnt[] array);
//  (b) main's ballot threshold 1e-20 -> 1e-8: denominator stays exact (all w
//      summed), only sub-1e-8 PV row-gathers are skipped (~2e-7 relative).

constexpr int Bb = 4;
constexpr int Tt = 4096;
constexpr int Hh = 256;
constexpr int NB = 1024;     // t-buckets per batch
// coverage: |dt| <= 2/1024 <=> w >= exp(-64); buckets [k-2, k+2] suffice.

// ---------------------------------------------------------------------------
// Per-batch counting sort. One block (1024 thr) per batch.
// Output: spair[b][pos] = { bitcast(t*4096), original_idx }, offsets[b][NB+1].
__global__ __launch_bounds__(1024) void sort_kernel(
    const float* __restrict__ tvals,
    uint2* __restrict__ spair,
    int* __restrict__ offsets)
{
    __shared__ int hist[NB];
    __shared__ int excl[NB];
    __shared__ int wsum[16];
    __shared__ int wexcl[16];

    const int b    = blockIdx.x;
    const int tid  = threadIdx.x;
    const int lane = tid & 63;
    const int wv   = tid >> 6;
    const float* tb = tvals + (size_t)b * Tt;

    hist[tid] = 0;
    __syncthreads();

    float tv[4]; int bk[4]; int rk[4];
    #pragma unroll
    for (int i = 0; i < 4; ++i) {
        const int j = i * 1024 + tid;
        const float t = tb[j];
        int k = (int)(t * (float)NB);
        k = k < 0 ? 0 : (k > NB - 1 ? NB - 1 : k);
        tv[i] = t * 4096.0f;      // pre-scaled for the main kernel
        bk[i] = k;
        rk[i] = atomicAdd(&hist[k], 1);   // rank within bucket (reused below)
    }
    __syncthreads();

    // inclusive scan over 1024 buckets: wave scan + cross-wave fixup
    const int self = hist[tid];
    int x = self;
    #pragma unroll
    for (int d = 1; d < 64; d <<= 1) {
        const int y = __shfl_up(x, d);
        if (lane >= d) x += y;
    }
    if (lane == 63) wsum[wv] = x;
    __syncthreads();
    if (tid < 16) {
        int y = wsum[tid];
        #pragma unroll
        for (int d = 1; d < 16; d <<= 1) {
            const int z = __shfl_up(y, d);
            if (tid >= d) y += z;
        }
        wexcl[tid] = y - wsum[tid];
    }
    __syncthreads();
    const int incl = x + wexcl[wv];
    excl[tid] = incl - self;
    offsets[(size_t)b * (NB + 1) + tid] = incl - self;
    if (tid == 0) offsets[(size_t)b * (NB + 1) + NB] = Tt;
    __syncthreads();

    #pragma unroll
    for (int i = 0; i < 4; ++i) {
        const int pos = excl[bk[i]] + rk[i];
        uint2 pr;
        pr.x = __float_as_uint(tv[i]);
        pr.y = (unsigned)(i * 1024 + tid);
        spair[(size_t)b * Tt + pos] = pr;
    }
}

// ---------------------------------------------------------------------------
// Main sparse kernel: 256 thr = 4 waves; each wave handles QPW=8 consecutive
// sorted queries (shared candidate window). Grid = B * T/32 = 512 blocks.
constexpr int QPW = 8;
constexpr int MTHREADS = 256;

__global__ __launch_bounds__(MTHREADS) void stattn_sparse(
    const float* __restrict__ h_seq,
    const uint2* __restrict__ spair,
    const int* __restrict__ offsets,
    float* __restrict__ out)
{
    const int tid  = threadIdx.x;
    const int lane = tid & 63;
    const int wv   = tid >> 6;

    // XCD-contiguous swizzle (512 blocks = 8 XCDs x 64): 2 XCDs per batch.
    const int phys = blockIdx.x;
    const int lb   = (phys & 7) * 64 + (phys >> 3);
    const int b    = lb >> 7;
    const int blk  = lb & 127;

    const uint2* sp  = spair + (size_t)b * Tt;
    const int*   off = offsets + (size_t)b * (NB + 1);
    const float* hb  = h_seq + (size_t)b * Tt * Hh;

    const int p0 = blk * 32 + wv * QPW;

    float tq[QPW]; int qi[QPW];
    #pragma unroll
    for (int g = 0; g < QPW; ++g) {
        const uint2 pr = sp[p0 + g];
        tq[g] = __uint_as_float(pr.x);     // t*4096
        qi[g] = (int)pr.y;
    }

    // candidate window (buckets nondecreasing along sorted positions)
    // bucket = floor(t*1024) = floor(ts * 0.25)
    int bmin = (int)(tq[0] * 0.25f);
    int bmax = (int)(tq[QPW - 1] * 0.25f);
    bmin = bmin < 0 ? 0 : (bmin > NB - 1 ? NB - 1 : bmin);
    bmax = bmax < 0 ? 0 : (bmax > NB - 1 ? NB - 1 : bmax);
    const int blo = bmin - 2 < 0 ? 0 : bmin - 2;
    const int bhi = bmax + 3 > NB ? NB : bmax + 3;
    const int lo = off[blo];
    const int hi = off[bhi];

    float4 acc[QPW];
    float  den[QPW];
    #pragma unroll
    for (int g = 0; g < QPW; ++g) {
        acc[g] = make_float4(0.f, 0.f, 0.f, 0.f);
        den[g] = 0.f;
    }

    for (int base = lo; base < hi; base += 64) {
        const int p = base + lane;
        const bool valid = p < hi;
        float tj; int jj;
        if (valid) { const uint2 pr = sp[p]; tj = __uint_as_float(pr.x); jj = (int)pr.y; }
        else       { tj = 3.0e18f; jj = 0; }   // -> w == 0 exactly

        float w[QPW]; float wmax = 0.f;
        #pragma unroll
        for (int g = 0; g < QPW; ++g) {
            const float x = tq[g] - tj;
            w[g] = __expf(-x * x);
            den[g] += w[g];                  // denominator: ALL terms (exact)
            wmax = fmaxf(wmax, w[g]);
        }

        // PV gather: skip rows whose max weight over this wave's 8 queries is
        // < 1e-8 (dropped PV mass < ~2e-7 relative; threshold budget 8.9e-2).
        unsigned long long mask = __ballot(wmax > 1e-8f);
        while (mask) {
            const int s0 = __builtin_ctzll(mask); mask &= mask - 1;
            const bool h1 = mask != 0;
            const int s1 = h1 ? __builtin_ctzll(mask) : s0; if (h1) mask &= mask - 1;
            const bool h2 = mask != 0;
            const int s2 = h2 ? __builtin_ctzll(mask) : s0; if (h2) mask &= mask - 1;
            const bool h3 = mask != 0;
            const int s3 = h3 ? __builtin_ctzll(mask) : s0; if (h3) mask &= mask - 1;

            const int j0 = __shfl(jj, s0);
            const int j1 = __shfl(jj, s1);
            const int j2 = __shfl(jj, s2);
            const int j3 = __shfl(jj, s3);
            float4 h0 = *(const float4*)&hb[(size_t)j0 * Hh + lane * 4];
            float4 h1v = *(const float4*)&hb[(size_t)j1 * Hh + lane * 4];
            float4 h2v = *(const float4*)&hb[(size_t)j2 * Hh + lane * 4];
            float4 h3v = *(const float4*)&hb[(size_t)j3 * Hh + lane * 4];
            // mask out duplicated slots once (amortized over all QPW queries)
            if (!h1) { h1v.x = 0.f; h1v.y = 0.f; h1v.z = 0.f; h1v.w = 0.f; }
            if (!h2) { h2v.x = 0.f; h2v.y = 0.f; h2v.z = 0.f; h2v.w = 0.f; }
            if (!h3) { h3v.x = 0.f; h3v.y = 0.f; h3v.z = 0.f; h3v.w = 0.f; }

            #pragma unroll
            for (int g = 0; g < QPW; ++g) {
                const float a0 = __shfl(w[g], s0);
                const float a1 = __shfl(w[g], s1);
                const float a2 = __shfl(w[g], s2);
                const float a3 = __shfl(w[g], s3);
                acc[g].x += a0 * h0.x; acc[g].y += a0 * h0.y;
                acc[g].z += a0 * h0.z; acc[g].w += a0 * h0.w;
                acc[g].x += a1 * h1v.x; acc[g].y += a1 * h1v.y;
                acc[g].z += a1 * h1v.z; acc[g].w += a1 * h1v.w;
                acc[g].x += a2 * h2v.x; acc[g].y += a2 * h2v.y;
                acc[g].z += a2 * h2v.z; acc[g].w += a2 * h2v.w;
                acc[g].x += a3 * h3v.x; acc[g].y += a3 * h3v.y;
                acc[g].z += a3 * h3v.z; acc[g].w += a3 * h3v.w;
            }
        }
    }

    // reduce denominators across lanes
    #pragma unroll
    for (int g = 0; g < QPW; ++g) {
        float d = den[g];
        #pragma unroll
        for (int s = 1; s < 64; s <<= 1) d += __shfl_xor(d, s);
        den[g] = d;
    }

    #pragma unroll
    for (int g = 0; g < QPW; ++g) {
        const float inv = 1.0f / den[g];
        float* orow = out + ((size_t)b * Tt + qi[g]) * Hh + lane * 4;
        float4 o;
        o.x = acc[g].x * inv; o.y = acc[g].y * inv;
        o.z = acc[g].z * inv; o.w = acc[g].w * inv;
        *(float4*)orow = o;
    }
}

// ---------------------------------------------------------------------------
// Fallback dense f32 kernel (round-1 proven) if ws is too small.
constexpr int QB = 64;
constexpr int JB = 64;
constexpr int NT = Tt / JB;
constexpr int NTHREADS = 512;

__device__ __forceinline__ void gld16(const void* g, void* l) {
    __builtin_amdgcn_global_load_lds(
        (const __attribute__((address_space(1))) void*)g,
        (__attribute__((address_space(3))) void*)l, 16, 0, 0);
}
__device__ __forceinline__ void gld4(const void* g, void* l) {
    __builtin_amdgcn_global_load_lds(
        (const __attribute__((address_space(1))) void*)g,
        (__attribute__((address_space(3))) void*)l, 4, 0, 0);
}

__global__ __launch_bounds__(NTHREADS, 2) void stattn_kernel(
    const float* __restrict__ h_seq,
    const float* __restrict__ tvals,
    float* __restrict__ out)
{
    __shared__ float hbuf[2][JB][Hh];
    __shared__ float wbuf[JB][QB];
    __shared__ float tjbuf[2][JB];
    __shared__ float sden[QB];
    __shared__ float tqs[QB];

    const int tid  = threadIdx.x;
    const int lane = tid & 63;
    const int wv   = tid >> 6;
    const int phys = blockIdx.x;
    const int lb   = (phys & 7) * 32 + (phys >> 3);
    const int b    = lb >> 6;
    const int qt   = lb & 63;
    const int q0   = qt * QB;

    const float* hb = h_seq + (size_t)b * Tt * Hh;
    const float* tb = tvals + (size_t)b * Tt;

    if (tid < QB) { tqs[tid] = tb[q0 + tid]; sden[tid] = 0.0f; }

    float acc[8][4];
    #pragma unroll
    for (int k = 0; k < 8; ++k)
        #pragma unroll
        for (int c = 0; c < 4; ++c) acc[k][c] = 0.0f;

    const float Tf = (float)Tt;

    auto stage = [&](int buf, int tile) {
        const float* src = hb + (size_t)tile * JB * Hh;
        float* dst = &hbuf[buf][0][0];
        #pragma unroll
        for (int i = 0; i < 8; ++i) {
            const int off = i * (NTHREADS * 4) + tid * 4;
            gld16(src + off, dst + off);
        }
        gld4(tb + tile * JB + lane, &tjbuf[buf][lane]);
    };

    stage(0, 0);
    __syncthreads();

    const int qw = wv * 8;

    for (int t = 0; t < NT; ++t) {
        const int cur = t & 1;
        __syncthreads();
        {
            const int q  = tid & 63;
            const int jg = tid >> 6;
            const float tqv = tqs[q];
            const float4 tj0 = *(const float4*)&tjbuf[cur][jg * 8];
            const float4 tj1 = *(const float4*)&tjbuf[cur][jg * 8 + 4];
            const float tjv[8] = {tj0.x, tj0.y, tj0.z, tj0.w,
                                  tj1.x, tj1.y, tj1.z, tj1.w};
            float part = 0.0f;
            #pragma unroll
            for (int jj = 0; jj < 8; ++jj) {
                const float d = Tf * (tqv - tjv[jj]);
                const float w = __expf(-d * d);
                wbuf[jg * 8 + jj][q] = w;
                part += w;
            }
            atomicAdd(&sden[q], part);
        }
        if (t + 1 < NT) stage((t + 1) & 1, t + 1);
        asm volatile("s_waitcnt lgkmcnt(0)" ::: "memory");
        __builtin_amdgcn_s_barrier();
        asm volatile("" ::: "memory");
        #pragma unroll 2
        for (int j = 0; j < JB; ++j) {
            const float4 hv = *(const float4*)&hbuf[cur][j][lane * 4];
            const float4 w0 = *(const float4*)&wbuf[j][qw];
            const float4 w1 = *(const float4*)&wbuf[j][qw + 4];
            const float wr[8] = {w0.x, w0.y, w0.z, w0.w,
                                 w1.x, w1.y, w1.z, w1.w};
            #pragma unroll
            for (int k = 0; k < 8; ++k) {
                acc[k][0] += wr[k] * hv.x;
                acc[k][1] += wr[k] * hv.y;
                acc[k][2] += wr[k] * hv.z;
                acc[k][3] += wr[k] * hv.w;
            }
        }
    }

    #pragma unroll
    for (int k = 0; k < 8; ++k) {
        const int q = q0 + qw + k;
        const float inv = 1.0f / sden[qw + k];
        float4 o;
        o.x = acc[k][0] * inv;
        o.y = acc[k][1] * inv;
        o.z = acc[k][2] * inv;
        o.w = acc[k][3] * inv;
        *(float4*)&out[((size_t)b * Tt + q) * Hh + (size_t)(lane * 4)] = o;
    }
}

extern "C" void kernel_launch(void* const* d_in, const int* in_sizes, int n_in,
                              void* d_out, int out_size, void* d_ws, size_t ws_size,
                              hipStream_t stream) {
    const float* h_seq = (const float*)d_in[0];
    const float* tvals = (const float*)d_in[1];
    float* out = (float*)d_out;

    // ws layout: spair (B*T uint2) | offsets (B*(NB+1) i32)
    const size_t need = (size_t)Bb * Tt * sizeof(uint2) + (size_t)Bb * (NB + 1) * 4;
    if (ws_size >= need) {
        uint2* spair  = (uint2*)d_ws;
        int*   offsets = (int*)(spair + (size_t)Bb * Tt);
        sort_kernel<<<dim3(Bb), dim3(1024), 0, stream>>>(tvals, spair, offsets);
        stattn_sparse<<<dim3(Bb * (Tt / 32)), dim3(MTHREADS), 0, stream>>>(
            h_seq, spair, offsets, out);
    } else {
        stattn_kernel<<<dim3(Bb * (Tt / QB)), dim3(NTHREADS), 0, stream>>>(
            h_seq, tvals, out);
    }
}

// Round 15
// 21.004 us; speedup vs baseline: 9.4259x; 1.0154x over previous
//
#include <hip/hip_runtime.h>
#include <hip/hip_bf16.h>

// SoftTimeAttention: out[b,q,:] = sum_j softmax_j(-(T*(t_q-t_j))^2) * h[b,j,:]
// B=4, T=4096, H=256, f32. w = exp(-(4096*dt)^2) == 0 in f32 for |dt| > ~2.3e-3
// => ~19 active keys per query. Bucket-sort t (1024 buckets), process queries in
// sorted order; each wave shares one candidate window across QPW queries.
//
// R15 = R14 (21.3 us) + two micro-opts:
//  (a) PV ballot threshold 1e-8 -> 1e-4 (den stays exact; dropped PV mass
//      ~2e-3 relative vs 8.9e-2 budget; active rows/round ~9 -> ~6);
//  (b) exp(-x^2) = exp2(-(x*s)^2), s=sqrt(log2 e): pre-scale tq once per wave
//      and tj once per lane-round, removing the per-pair log2e multiply.
//      Bucket math stays on the exact power-of-2 t*4096 scale.

constexpr int Bb = 4;
constexpr int Tt = 4096;
constexpr int Hh = 256;
constexpr int NB = 1024;     // t-buckets per batch
// coverage: |dt| <= 2/1024 <=> w >= exp(-64); buckets [k-2, k+2] suffice.

// ---------------------------------------------------------------------------
// Per-batch counting sort. One block (1024 thr) per batch.
// Output: spair[b][pos] = { bitcast(t*4096), original_idx }, offsets[b][NB+1].
__global__ __launch_bounds__(1024) void sort_kernel(
    const float* __restrict__ tvals,
    uint2* __restrict__ spair,
    int* __restrict__ offsets)
{
    __shared__ int hist[NB];
    __shared__ int excl[NB];
    __shared__ int wsum[16];
    __shared__ int wexcl[16];

    const int b    = blockIdx.x;
    const int tid  = threadIdx.x;
    const int lane = tid & 63;
    const int wv   = tid >> 6;
    const float* tb = tvals + (size_t)b * Tt;

    hist[tid] = 0;
    __syncthreads();

    float tv[4]; int bk[4]; int rk[4];
    #pragma unroll
    for (int i = 0; i < 4; ++i) {
        const int j = i * 1024 + tid;
        const float t = tb[j];
        int k = (int)(t * (float)NB);
        k = k < 0 ? 0 : (k > NB - 1 ? NB - 1 : k);
        tv[i] = t * 4096.0f;      // pre-scaled (power of 2: exact buckets)
        bk[i] = k;
        rk[i] = atomicAdd(&hist[k], 1);   // rank within bucket (reused below)
    }
    __syncthreads();

    // inclusive scan over 1024 buckets: wave scan + cross-wave fixup
    const int self = hist[tid];
    int x = self;
    #pragma unroll
    for (int d = 1; d < 64; d <<= 1) {
        const int y = __shfl_up(x, d);
        if (lane >= d) x += y;
    }
    if (lane == 63) wsum[wv] = x;
    __syncthreads();
    if (tid < 16) {
        int y = wsum[tid];
        #pragma unroll
        for (int d = 1; d < 16; d <<= 1) {
            const int z = __shfl_up(y, d);
            if (tid >= d) y += z;
        }
        wexcl[tid] = y - wsum[tid];
    }
    __syncthreads();
    const int incl = x + wexcl[wv];
    excl[tid] = incl - self;
    offsets[(size_t)b * (NB + 1) + tid] = incl - self;
    if (tid == 0) offsets[(size_t)b * (NB + 1) + NB] = Tt;
    __syncthreads();

    #pragma unroll
    for (int i = 0; i < 4; ++i) {
        const int pos = excl[bk[i]] + rk[i];
        uint2 pr;
        pr.x = __float_as_uint(tv[i]);
        pr.y = (unsigned)(i * 1024 + tid);
        spair[(size_t)b * Tt + pos] = pr;
    }
}

// ---------------------------------------------------------------------------
// Main sparse kernel: 256 thr = 4 waves; each wave handles QPW=8 consecutive
// sorted queries (shared candidate window). Grid = B * T/32 = 512 blocks.
constexpr int QPW = 8;
constexpr int MTHREADS = 256;

__global__ __launch_bounds__(MTHREADS) void stattn_sparse(
    const float* __restrict__ h_seq,
    const uint2* __restrict__ spair,
    const int* __restrict__ offsets,
    float* __restrict__ out)
{
    const int tid  = threadIdx.x;
    const int lane = tid & 63;
    const int wv   = tid >> 6;

    // XCD-contiguous swizzle (512 blocks = 8 XCDs x 64): 2 XCDs per batch.
    const int phys = blockIdx.x;
    const int lb   = (phys & 7) * 64 + (phys >> 3);
    const int b    = lb >> 7;
    const int blk  = lb & 127;

    const uint2* sp  = spair + (size_t)b * Tt;
    const int*   off = offsets + (size_t)b * (NB + 1);
    const float* hb  = h_seq + (size_t)b * Tt * Hh;

    const int p0 = blk * 32 + wv * QPW;

    float tq[QPW]; int qi[QPW];
    #pragma unroll
    for (int g = 0; g < QPW; ++g) {
        const uint2 pr = sp[p0 + g];
        tq[g] = __uint_as_float(pr.x);     // t*4096
        qi[g] = (int)pr.y;
    }

    // candidate window (buckets nondecreasing along sorted positions)
    // bucket = floor(t*1024) = floor(ts * 0.25)  [exact: power-of-2 scales]
    int bmin = (int)(tq[0] * 0.25f);
    int bmax = (int)(tq[QPW - 1] * 0.25f);
    bmin = bmin < 0 ? 0 : (bmin > NB - 1 ? NB - 1 : bmin);
    bmax = bmax < 0 ? 0 : (bmax > NB - 1 ? NB - 1 : bmax);
    const int blo = bmin - 2 < 0 ? 0 : bmin - 2;
    const int bhi = bmax + 3 > NB ? NB : bmax + 3;
    const int lo = off[blo];
    const int hi = off[bhi];

    // exp2 rescale: exp(-x^2) = exp2(-(x*s)^2), s = sqrt(log2 e).
    const float SLN = 1.2011224087864498f;
    #pragma unroll
    for (int g = 0; g < QPW; ++g) tq[g] *= SLN;

    float4 acc[QPW];
    float  den[QPW];
    #pragma unroll
    for (int g = 0; g < QPW; ++g) {
        acc[g] = make_float4(0.f, 0.f, 0.f, 0.f);
        den[g] = 0.f;
    }

    for (int base = lo; base < hi; base += 64) {
        const int p = base + lane;
        const bool valid = p < hi;
        float tj; int jj;
        if (valid) { const uint2 pr = sp[p]; tj = __uint_as_float(pr.x); jj = (int)pr.y; }
        else       { tj = 3.0e18f; jj = 0; }   // -> w == 0 exactly

        const float tj2 = tj * SLN;

        float w[QPW]; float wmax = 0.f;
        #pragma unroll
        for (int g = 0; g < QPW; ++g) {
            const float x = tq[g] - tj2;
            w[g] = exp2f(-(x * x));
            den[g] += w[g];                  // denominator: ALL terms (exact)
            wmax = fmaxf(wmax, w[g]);
        }

        // PV gather: skip rows whose max weight over this wave's 8 queries is
        // < 1e-4 (dropped PV mass ~2e-3 relative; threshold budget 8.9e-2).
        unsigned long long mask = __ballot(wmax > 1e-4f);
        while (mask) {
            const int s0 = __builtin_ctzll(mask); mask &= mask - 1;
            const bool h1 = mask != 0;
            const int s1 = h1 ? __builtin_ctzll(mask) : s0; if (h1) mask &= mask - 1;
            const bool h2 = mask != 0;
            const int s2 = h2 ? __builtin_ctzll(mask) : s0; if (h2) mask &= mask - 1;
            const bool h3 = mask != 0;
            const int s3 = h3 ? __builtin_ctzll(mask) : s0; if (h3) mask &= mask - 1;

            const int j0 = __shfl(jj, s0);
            const int j1 = __shfl(jj, s1);
            const int j2 = __shfl(jj, s2);
            const int j3 = __shfl(jj, s3);
            float4 h0 = *(const float4*)&hb[(size_t)j0 * Hh + lane * 4];
            float4 h1v = *(const float4*)&hb[(size_t)j1 * Hh + lane * 4];
            float4 h2v = *(const float4*)&hb[(size_t)j2 * Hh + lane * 4];
            float4 h3v = *(const float4*)&hb[(size_t)j3 * Hh + lane * 4];
            // mask out duplicated slots once (amortized over all QPW queries)
            if (!h1) { h1v.x = 0.f; h1v.y = 0.f; h1v.z = 0.f; h1v.w = 0.f; }
            if (!h2) { h2v.x = 0.f; h2v.y = 0.f; h2v.z = 0.f; h2v.w = 0.f; }
            if (!h3) { h3v.x = 0.f; h3v.y = 0.f; h3v.z = 0.f; h3v.w = 0.f; }

            #pragma unroll
            for (int g = 0; g < QPW; ++g) {
                const float a0 = __shfl(w[g], s0);
                const float a1 = __shfl(w[g], s1);
                const float a2 = __shfl(w[g], s2);
                const float a3 = __shfl(w[g], s3);
                acc[g].x += a0 * h0.x; acc[g].y += a0 * h0.y;
                acc[g].z += a0 * h0.z; acc[g].w += a0 * h0.w;
                acc[g].x += a1 * h1v.x; acc[g].y += a1 * h1v.y;
                acc[g].z += a1 * h1v.z; acc[g].w += a1 * h1v.w;
                acc[g].x += a2 * h2v.x; acc[g].y += a2 * h2v.y;
                acc[g].z += a2 * h2v.z; acc[g].w += a2 * h2v.w;
                acc[g].x += a3 * h3v.x; acc[g].y += a3 * h3v.y;
                acc[g].z += a3 * h3v.z; acc[g].w += a3 * h3v.w;
            }
        }
    }

    // reduce denominators across lanes
    #pragma unroll
    for (int g = 0; g < QPW; ++g) {
        float d = den[g];
        #pragma unroll
        for (int s = 1; s < 64; s <<= 1) d += __shfl_xor(d, s);
        den[g] = d;
    }

    #pragma unroll
    for (int g = 0; g < QPW; ++g) {
        const float inv = 1.0f / den[g];
        float* orow = out + ((size_t)b * Tt + qi[g]) * Hh + lane * 4;
        float4 o;
        o.x = acc[g].x * inv; o.y = acc[g].y * inv;
        o.z = acc[g].z * inv; o.w = acc[g].w * inv;
        *(float4*)orow = o;
    }
}

// ---------------------------------------------------------------------------
// Fallback dense f32 kernel (round-1 proven) if ws is too small.
constexpr int QB = 64;
constexpr int JB = 64;
constexpr int NT = Tt / JB;
constexpr int NTHREADS = 512;

__device__ __forceinline__ void gld16(const void* g, void* l) {
    __builtin_amdgcn_global_load_lds(
        (const __attribute__((address_space(1))) void*)g,
        (__attribute__((address_space(3))) void*)l, 16, 0, 0);
}
__device__ __forceinline__ void gld4(const void* g, void* l) {
    __builtin_amdgcn_global_load_lds(
        (const __attribute__((address_space(1))) void*)g,
        (__attribute__((address_space(3))) void*)l, 4, 0, 0);
}

__global__ __launch_bounds__(NTHREADS, 2) void stattn_kernel(
    const float* __restrict__ h_seq,
    const float* __restrict__ tvals,
    float* __restrict__ out)
{
    __shared__ float hbuf[2][JB][Hh];
    __shared__ float wbuf[JB][QB];
    __shared__ float tjbuf[2][JB];
    __shared__ float sden[QB];
    __shared__ float tqs[QB];

    const int tid  = threadIdx.x;
    const int lane = tid & 63;
    const int wv   = tid >> 6;
    const int phys = blockIdx.x;
    const int lb   = (phys & 7) * 32 + (phys >> 3);
    const int b    = lb >> 6;
    const int qt   = lb & 63;
    const int q0   = qt * QB;

    const float* hb = h_seq + (size_t)b * Tt * Hh;
    const float* tb = tvals + (size_t)b * Tt;

    if (tid < QB) { tqs[tid] = tb[q0 + tid]; sden[tid] = 0.0f; }

    float acc[8][4];
    #pragma unroll
    for (int k = 0; k < 8; ++k)
        #pragma unroll
        for (int c = 0; c < 4; ++c) acc[k][c] = 0.0f;

    const float Tf = (float)Tt;

    auto stage = [&](int buf, int tile) {
        const float* src = hb + (size_t)tile * JB * Hh;
        float* dst = &hbuf[buf][0][0];
        #pragma unroll
        for (int i = 0; i < 8; ++i) {
            const int off = i * (NTHREADS * 4) + tid * 4;
            gld16(src + off, dst + off);
        }
        gld4(tb + tile * JB + lane, &tjbuf[buf][lane]);
    };

    stage(0, 0);
    __syncthreads();

    const int qw = wv * 8;

    for (int t = 0; t < NT; ++t) {
        const int cur = t & 1;
        __syncthreads();
        {
            const int q  = tid & 63;
            const int jg = tid >> 6;
            const float tqv = tqs[q];
            const float4 tj0 = *(const float4*)&tjbuf[cur][jg * 8];
            const float4 tj1 = *(const float4*)&tjbuf[cur][jg * 8 + 4];
            const float tjv[8] = {tj0.x, tj0.y, tj0.z, tj0.w,
                                  tj1.x, tj1.y, tj1.z, tj1.w};
            float part = 0.0f;
            #pragma unroll
            for (int jj = 0; jj < 8; ++jj) {
                const float d = Tf * (tqv - tjv[jj]);
                const float w = __expf(-d * d);
                wbuf[jg * 8 + jj][q] = w;
                part += w;
            }
            atomicAdd(&sden[q], part);
        }
        if (t + 1 < NT) stage((t + 1) & 1, t + 1);
        asm volatile("s_waitcnt lgkmcnt(0)" ::: "memory");
        __builtin_amdgcn_s_barrier();
        asm volatile("" ::: "memory");
        #pragma unroll 2
        for (int j = 0; j < JB; ++j) {
            const float4 hv = *(const float4*)&hbuf[cur][j][lane * 4];
            const float4 w0 = *(const float4*)&wbuf[j][qw];
            const float4 w1 = *(const float4*)&wbuf[j][qw + 4];
            const float wr[8] = {w0.x, w0.y, w0.z, w0.w,
                                 w1.x, w1.y, w1.z, w1.w};
            #pragma unroll
            for (int k = 0; k < 8; ++k) {
                acc[k][0] += wr[k] * hv.x;
                acc[k][1] += wr[k] * hv.y;
                acc[k][2] += wr[k] * hv.z;
                acc[k][3] += wr[k] * hv.w;
            }
        }
    }

    #pragma unroll
    for (int k = 0; k < 8; ++k) {
        const int q = q0 + qw + k;
        const float inv = 1.0f / sden[qw + k];
        float4 o;
        o.x = acc[k][0] * inv;
        o.y = acc[k][1] * inv;
        o.z = acc[k][2] * inv;
        o.w = acc[k][3] * inv;
        *(float4*)&out[((size_t)b * Tt + q) * Hh + (size_t)(lane * 4)] = o;
    }
}

extern "C" void kernel_launch(void* const* d_in, const int* in_sizes, int n_in,
                              void* d_out, int out_size, void* d_ws, size_t ws_size,
                              hipStream_t stream) {
    const float* h_seq = (const float*)d_in[0];
    const float* tvals = (const float*)d_in[1];
    float* out = (float*)d_out;

    // ws layout: spair (B*T uint2) | offsets (B*(NB+1) i32)
    const size_t need = (size_t)Bb * Tt * sizeof(uint2) + (size_t)Bb * (NB + 1) * 4;
    if (ws_size >= need) {
        uint2* spair  = (uint2*)d_ws;
        int*   offsets = (int*)(spair + (size_t)Bb * Tt);
        sort_kernel<<<dim3(Bb), dim3(1024), 0, stream>>>(tvals, spair, offsets);
        stattn_sparse<<<dim3(Bb * (Tt / 32)), dim3(MTHREADS), 0, stream>>>(
            h_seq, spair, offsets, out);
    } else {
        stattn_kernel<<<dim3(Bb * (Tt / QB)), dim3(NTHREADS), 0, stream>>>(
            h_seq, tvals, out);
    }
}